// Round 16
// baseline (114.355 us; speedup 1.0000x reference)
//
#include <hip/hip_runtime.h>
#include <hip/hip_bf16.h>

typedef short bf16x8 __attribute__((ext_vector_type(8)));
typedef float f32x4 __attribute__((ext_vector_type(4)));
typedef float f32x16 __attribute__((ext_vector_type(16)));
typedef long l64x2 __attribute__((ext_vector_type(2)));
typedef unsigned short u16;
typedef unsigned char u8;

#define NB2 (-0.35f * 1.44269504088896340736f)
#define P2C (0.70f * 1.44269504088896340736f)
#define MF8(a,b,c)  __builtin_amdgcn_mfma_f32_32x32x16_fp8_fp8(a, b, c, 0, 0, 0)
#define MFB(a,b,c)  __builtin_amdgcn_mfma_f32_32x32x16_bf16(a, b, c, 0, 0, 0)

__device__ __forceinline__ u16 f2bf(float f) {
  union { float f; unsigned int u; } v; v.f = f;
  unsigned int x = v.u;
  return (u16)((x + 0x7FFFu + ((x >> 16) & 1u)) >> 16);
}

__device__ __forceinline__ unsigned cvtpk(float lo, float hi) {
  unsigned r;
  asm("v_cvt_pk_bf16_f32 %0, %1, %2" : "=v"(r) : "v"(lo), "v"(hi));
  return r;
}

__device__ __forceinline__ void pswap(unsigned &a, unsigned &b) {
  asm volatile("v_permlane32_swap_b32 %0, %1" : "+v"(a), "+v"(b));
}

__device__ __forceinline__ u8 f2e4m3(float f) {
  unsigned int u = __float_as_uint(f);
  u8 s = (u8)((u >> 24) & 0x80u);
  float a = fabsf(f);
  if (a >= 448.f) return s | 0x7E;
  if (a < 0.015625f) return s | (u8)(int)rintf(a * 512.f);
  unsigned int m = u & 0x7fffffffu;
  unsigned int r = m + 0x7FFFFu + ((m >> 20) & 1u);
  return s | (u8)((((r >> 23) - 120u) << 3) | ((r >> 20) & 7u));
}

__device__ __forceinline__ unsigned int pk4(float a, float b, float c, float d) {
#if __has_builtin(__builtin_amdgcn_cvt_pk_fp8_f32)
  int v = __builtin_amdgcn_cvt_pk_fp8_f32(a, b, 0, false);
  v = __builtin_amdgcn_cvt_pk_fp8_f32(c, d, v, true);
  return (unsigned int)v;
#else
  return (unsigned int)f2e4m3(a) | ((unsigned int)f2e4m3(b) << 8)
       | ((unsigned int)f2e4m3(c) << 16) | ((unsigned int)f2e4m3(d) << 24);
#endif
}

#define GLOAD_LDS(g, l) __builtin_amdgcn_global_load_lds( \
    (const __attribute__((address_space(1))) unsigned int*)(g), \
    (__attribute__((address_space(3))) unsigned int*)(l), 16, 0, 0)

// ---------- prep: fp32 rows -> fp8 frag-stream [tile32][p(16)][lane(64)][16B] + row sumsq ----------
// lane l = (h<<5)|(row&31); 16B unit at p: sub0 = k[p*32+h*8 ..+8), sub1 = k[p*32+16+h*8 ..+8)
__global__ __launch_bounds__(512)
void prep_f8s(const float* __restrict__ src, u8* __restrict__ dst,
              float* __restrict__ sq) {
  const int row = blockIdx.x * 8 + (threadIdx.x >> 6);
  const int i6 = threadIdx.x & 63;
  const float4* p = (const float4*)(src + (size_t)row * 512) + i6 * 2;
  float4 a = p[0], b = p[1];
  float ss = a.x*a.x + a.y*a.y + a.z*a.z + a.w*a.w
           + b.x*b.x + b.y*b.y + b.z*b.z + b.w*b.w;
  uint2 o;
  o.x = pk4(a.x, a.y, a.z, a.w);
  o.y = pk4(b.x, b.y, b.z, b.w);
  const int pp = i6 >> 2, sub = (i6 >> 1) & 1, h = i6 & 1;
  const int l = (h << 5) | (row & 31);
  *(uint2*)(dst + (size_t)(row >> 5) * 16384 + pp * 1024 + l * 16 + sub * 8) = o;
  ss += __shfl_xor(ss, 1);  ss += __shfl_xor(ss, 2);
  ss += __shfl_xor(ss, 4);  ss += __shfl_xor(ss, 8);
  ss += __shfl_xor(ss, 16); ss += __shfl_xor(ss, 32);
  if (i6 == 0) sq[row] = ss;
}

// ---------- prep: W [4096][128] f32 -> per-lane-contig bf16 B-frag stream ----------
// element (o,c): byte = (c>>5)*8192 + (o>>5)*2048 + (((c&31)>>4))*1024
//                     + ((((c&15)>>3)*32) + (o&31))*16 + (c&7)*2
__global__ __launch_bounds__(256)
void prep_w(const float* __restrict__ W, u8* __restrict__ wt) {
  __shared__ u16 t_[128 * 66];
  const int c0 = blockIdx.x * 64;
  const int t = threadIdx.x;
#pragma unroll
  for (int it = 0; it < 32; ++it) {
    int idx = it * 256 + t;
    int cl = idx >> 7;
    int o  = idx & 127;
    t_[o * 66 + cl] = f2bf(W[(size_t)(c0 + cl) * 128 + o]);
  }
  __syncthreads();
#pragma unroll
  for (int it = 0; it < 4; ++it) {
    int idx = it * 256 + t;            // 0..1023 : 16B units
    int o  = idx >> 3;
    int uu = idx & 7;
    int ch = uu >> 2;                  // local chunk 0/1
    int kt = (uu >> 1) & 1;
    int h  = uu & 1;
    u16* d = (u16*)(wt + ((size_t)(c0 >> 5) + ch) * 8192 + (o >> 5) * 2048
                    + kt * 1024 + (h * 32 + (o & 31)) * 16);
    const u16* s_ = &t_[o * 66 + ch * 32 + kt * 16 + h * 8];
#pragma unroll
    for (int j = 0; j < 8; ++j) d[j] = s_[j];
  }
}

// ---------- init: out = bias ----------
__global__ __launch_bounds__(256)
void init_out(const float* __restrict__ bias, float* __restrict__ out) {
  const int i4 = blockIdx.x * 256 + threadIdx.x;
  float4 b = ((const float4*)bias)[i4 & 31];
  ((float4*)out)[i4] = b;
}

// ---------- main: 256 blocks(512thr) = 64 row-tiles(256r) x 4 quarters ----------
// Barrier-free main loop: all MFMA operands direct from L1/L2 frag-streams; no LDS tiles.
__global__ __launch_bounds__(512, 2)
void rbf_main(const u8* __restrict__ xfs, const u8* __restrict__ cfr,
              const u8* __restrict__ wfr, const float* __restrict__ csq_g,
              const float* __restrict__ xsq_g, float* __restrict__ out)
{
  __shared__ __align__(16) float csq_l[1024];
  __shared__ __align__(16) float xsq_l[256];

  const int tid = threadIdx.x;
  const int lane = tid & 63;
  const int wv = tid >> 6;                 // wave 0..7 -> rows wv*32..+32
  const int l31 = lane & 31;
  const int h = lane >> 5;
  const int bid = blockIdx.x;
  const int chq = bid & 3;
  const size_t r0 = (size_t)(bid >> 2) * 256;

  // prologue: csq/xsq -> LDS (read-only thereafter), x fragments -> regs
  if (tid < 256) GLOAD_LDS(csq_g + chq * 1024 + tid * 4, csq_l + tid * 4);
  if (tid < 64)  GLOAD_LDS(xsq_g + r0 + tid * 4, xsq_l + tid * 4);

  l64x2 xf[16];
  {
    const u8* xb = xfs + ((size_t)((bid >> 2) * 8 + wv)) * 16384 + lane * 16;
#pragma unroll
    for (int p = 0; p < 16; ++p)
      xf[p] = *(const l64x2*)(xb + p * 1024);
  }

  asm volatile("s_waitcnt vmcnt(0)" ::: "memory");
  __builtin_amdgcn_s_barrier();            // the ONLY barrier in the kernel
  __builtin_amdgcn_sched_barrier(0);

  const float xn = NB2 * xsq_l[wv * 32 + l31];

  const f32x16 z16 = {0,0,0,0,0,0,0,0,0,0,0,0,0,0,0,0};
  f32x16 oa0 = z16, oa1 = z16, oa2 = z16, oa3 = z16;

#define G1Q(V0, V1, V2, V3, PB) do { \
    __builtin_amdgcn_s_setprio(1); \
    s0 = MF8(V0[0], xf[(PB) + 0][0], s0); \
    s1 = MF8(V0[1], xf[(PB) + 0][1], s1); \
    s0 = MF8(V1[0], xf[(PB) + 1][0], s0); \
    s1 = MF8(V1[1], xf[(PB) + 1][1], s1); \
    s0 = MF8(V2[0], xf[(PB) + 2][0], s0); \
    s1 = MF8(V2[1], xf[(PB) + 2][1], s1); \
    s0 = MF8(V3[0], xf[(PB) + 3][0], s0); \
    s1 = MF8(V3[1], xf[(PB) + 3][1], s1); \
    __builtin_amdgcn_s_setprio(0); \
  } while (0)

#pragma unroll 1
  for (int cc = 0; cc < 32; ++cc) {
    const u8* cgb = cfr + ((size_t)(chq * 32 + cc) << 14) + lane * 16;
    const u8* wgb = wfr + ((size_t)(chq * 32 + cc) << 13) + lane * 16;

    // centers group 0 (p0-3) + group 1 (p4-7)
    l64x2 A0 = *(const l64x2*)(cgb);
    l64x2 A1 = *(const l64x2*)(cgb + 1024);
    l64x2 A2 = *(const l64x2*)(cgb + 2048);
    l64x2 A3 = *(const l64x2*)(cgb + 3072);
    l64x2 B0 = *(const l64x2*)(cgb + 4096);
    l64x2 B1 = *(const l64x2*)(cgb + 5120);
    l64x2 B2 = *(const l64x2*)(cgb + 6144);
    l64x2 B3 = *(const l64x2*)(cgb + 7168);

    f32x16 s0 = z16, s1 = z16;
    G1Q(A0, A1, A2, A3, 0);

    // centers group 2 (p8-11)
    A0 = *(const l64x2*)(cgb + 8192);
    A1 = *(const l64x2*)(cgb + 9216);
    A2 = *(const l64x2*)(cgb + 10240);
    A3 = *(const l64x2*)(cgb + 11264);

    // W fragments (consumed at GEMM2, ~1500cy later)
    bf16x8 w00 = *(const bf16x8*)(wgb);
    bf16x8 w01 = *(const bf16x8*)(wgb + 1024);
    bf16x8 w10 = *(const bf16x8*)(wgb + 2048);
    bf16x8 w11 = *(const bf16x8*)(wgb + 3072);
    bf16x8 w20 = *(const bf16x8*)(wgb + 4096);
    bf16x8 w21 = *(const bf16x8*)(wgb + 5120);
    bf16x8 w30 = *(const bf16x8*)(wgb + 6144);
    bf16x8 w31 = *(const bf16x8*)(wgb + 7168);

    G1Q(B0, B1, B2, B3, 4);

    // centers group 3 (p12-15)
    B0 = *(const l64x2*)(cgb + 12288);
    B1 = *(const l64x2*)(cgb + 13312);
    B2 = *(const l64x2*)(cgb + 14336);
    B3 = *(const l64x2*)(cgb + 15360);

    G1Q(A0, A1, A2, A3, 8);
    G1Q(B0, B1, B2, B3, 12);

    // ---- rbf in registers: lane m=l31; reg r -> c = (r&3) + 8*(r>>2) + 4*h ----
    f32x4 cq0 = *(const f32x4*)(csq_l + cc * 32 + 0  + 4 * h);
    f32x4 cq1 = *(const f32x4*)(csq_l + cc * 32 + 8  + 4 * h);
    f32x4 cq2 = *(const f32x4*)(csq_l + cc * 32 + 16 + 4 * h);
    f32x4 cq3 = *(const f32x4*)(csq_l + cc * 32 + 24 + 4 * h);
    float e[16];
#pragma unroll
    for (int r = 0; r < 16; ++r) {
      const float cq = (r < 4 ? cq0[r] : r < 8 ? cq1[r - 4] : r < 12 ? cq2[r - 8] : cq3[r - 12]);
      e[r] = __builtin_amdgcn_exp2f(fmaf(s0[r] + s1[r], P2C, fmaf(cq, NB2, xn)));
    }
    unsigned P0 = cvtpk(e[0],  e[1]),  P1 = cvtpk(e[2],  e[3]);
    unsigned P2 = cvtpk(e[4],  e[5]),  P3 = cvtpk(e[6],  e[7]);
    unsigned P4 = cvtpk(e[8],  e[9]),  P5 = cvtpk(e[10], e[11]);
    unsigned P6 = cvtpk(e[12], e[13]), P7 = cvtpk(e[14], e[15]);
    pswap(P0, P2); pswap(P1, P3);      // F: c 0..15
    pswap(P4, P6); pswap(P5, P7);      // G: c 16..31
    union { unsigned u[4]; bf16x8 v; } FA, GA;
    FA.u[0] = P0; FA.u[1] = P1; FA.u[2] = P2; FA.u[3] = P3;
    GA.u[0] = P4; GA.u[1] = P5; GA.u[2] = P6; GA.u[3] = P7;

    // ---- GEMM2: D[m][o] += P(32m x 32c) x W(32c x 128o), all register operands ----
    __builtin_amdgcn_s_setprio(1);
    oa0 = MFB(FA.v, w00, oa0);
    oa0 = MFB(GA.v, w01, oa0);
    oa1 = MFB(FA.v, w10, oa1);
    oa1 = MFB(GA.v, w11, oa1);
    oa2 = MFB(FA.v, w20, oa2);
    oa2 = MFB(GA.v, w21, oa2);
    oa3 = MFB(FA.v, w30, oa3);
    oa3 = MFB(GA.v, w31, oa3);
    __builtin_amdgcn_s_setprio(0);
  }

  // epilogue: out += partial; D rows m=(r&3)+8*(r>>2)+4h, cols o=ot*32+l31
#pragma unroll
  for (int r = 0; r < 16; ++r) {
    const int m = wv * 32 + (r & 3) + 8 * (r >> 2) + 4 * h;
    float* op = &out[(r0 + m) * 128 + l31];
    atomicAdd(op,      oa0[r]);
    atomicAdd(op + 32, oa1[r]);
    atomicAdd(op + 64, oa2[r]);
    atomicAdd(op + 96, oa3[r]);
  }
#undef G1Q
}

extern "C" void kernel_launch(void* const* d_in, const int* in_sizes, int n_in,
                              void* d_out, int out_size, void* d_ws, size_t ws_size,
                              hipStream_t stream) {
  (void)in_sizes; (void)n_in; (void)out_size; (void)ws_size;
  const float* x   = (const float*)d_in[0];
  const float* cen = (const float*)d_in[1];
  const float* W   = (const float*)d_in[2];
  const float* b   = (const float*)d_in[3];
  u8* xfs = (u8*)d_ws;                          // 8 MB (x frag-stream)
  u8* cfr = xfs + (size_t)16384 * 512;          // 2 MB (center frag-stream)
  u8* wfr = cfr + (size_t)4096 * 512;           // 1 MB (W B-frag stream)
  float* csq = (float*)(wfr + (size_t)128 * 8192);  // 16 KB
  float* xsq = csq + 4096;                      // 64 KB
  prep_f8s<<<2048, 512, 0, stream>>>(x, xfs, xsq);
  prep_f8s<<<512, 512, 0, stream>>>(cen, cfr, csq);
  prep_w<<<64, 256, 0, stream>>>(W, wfr);
  init_out<<<2048, 256, 0, stream>>>(b, (float*)d_out);
  rbf_main<<<256, 512, 0, stream>>>(xfs, cfr, wfr, csq, xsq, (float*)d_out);
}

// Round 17
// 105.980 us; speedup vs baseline: 1.0790x; 1.0790x over previous
//
#include <hip/hip_runtime.h>
#include <hip/hip_bf16.h>

typedef short bf16x8 __attribute__((ext_vector_type(8)));
typedef float f32x4 __attribute__((ext_vector_type(4)));
typedef float f32x16 __attribute__((ext_vector_type(16)));
typedef long l64x2 __attribute__((ext_vector_type(2)));
typedef unsigned short u16;
typedef unsigned char u8;

#define NB2 (-0.35f * 1.44269504088896340736f)
#define P2C (0.70f * 1.44269504088896340736f)
#define MF8(a,b,c)  __builtin_amdgcn_mfma_f32_32x32x16_fp8_fp8(a, b, c, 0, 0, 0)
#define MFB(a,b,c)  __builtin_amdgcn_mfma_f32_32x32x16_bf16(a, b, c, 0, 0, 0)

__device__ __forceinline__ u16 f2bf(float f) {
  union { float f; unsigned int u; } v; v.f = f;
  unsigned int x = v.u;
  return (u16)((x + 0x7FFFu + ((x >> 16) & 1u)) >> 16);
}

__device__ __forceinline__ unsigned cvtpk(float lo, float hi) {
  unsigned r;
  asm("v_cvt_pk_bf16_f32 %0, %1, %2" : "=v"(r) : "v"(lo), "v"(hi));
  return r;
}

// exchange a.hi-lanes <-> b.lo-lanes
__device__ __forceinline__ void pswap(unsigned &a, unsigned &b) {
  asm volatile("v_permlane32_swap_b32 %0, %1" : "+v"(a), "+v"(b));
}

__device__ __forceinline__ u8 f2e4m3(float f) {
  unsigned int u = __float_as_uint(f);
  u8 s = (u8)((u >> 24) & 0x80u);
  float a = fabsf(f);
  if (a >= 448.f) return s | 0x7E;
  if (a < 0.015625f) return s | (u8)(int)rintf(a * 512.f);
  unsigned int m = u & 0x7fffffffu;
  unsigned int r = m + 0x7FFFFu + ((m >> 20) & 1u);
  return s | (u8)((((r >> 23) - 120u) << 3) | ((r >> 20) & 7u));
}

__device__ __forceinline__ unsigned int pk4(float a, float b, float c, float d) {
#if __has_builtin(__builtin_amdgcn_cvt_pk_fp8_f32)
  int v = __builtin_amdgcn_cvt_pk_fp8_f32(a, b, 0, false);
  v = __builtin_amdgcn_cvt_pk_fp8_f32(c, d, v, true);
  return (unsigned int)v;
#else
  return (unsigned int)f2e4m3(a) | ((unsigned int)f2e4m3(b) << 8)
       | ((unsigned int)f2e4m3(c) << 16) | ((unsigned int)f2e4m3(d) << 24);
#endif
}

#define GLOAD_LDS(g, l) __builtin_amdgcn_global_load_lds( \
    (const __attribute__((address_space(1))) unsigned int*)(g), \
    (__attribute__((address_space(3))) unsigned int*)(l), 16, 0, 0)

// ---------- prep: x -> fp8 frag-stream [rowtile(512)][p(16)][lane(64)]16B + xsq ----------
// lane unit (p,l): row m = l&31, h = l>>5; bytes = k{2p*16+h*8..+8} ++ k{(2p+1)*16+h*8..+8}
__global__ __launch_bounds__(512)
void prep_x8(const float* __restrict__ src, u8* __restrict__ dst,
             float* __restrict__ sq) {
  const int row = blockIdx.x * 8 + (threadIdx.x >> 6);
  const int i6 = threadIdx.x & 63;            // k granule: k in [i6*8, i6*8+8)
  const float4* p = (const float4*)(src + (size_t)row * 512) + i6 * 2;
  float4 a = p[0], b = p[1];
  float ss = a.x*a.x + a.y*a.y + a.z*a.z + a.w*a.w
           + b.x*b.x + b.y*b.y + b.z*b.z + b.w*b.w;
  uint2 o;
  o.x = pk4(a.x, a.y, a.z, a.w);
  o.y = pk4(b.x, b.y, b.z, b.w);
  const int pp = i6 >> 2, sub = (i6 >> 1) & 1, h = i6 & 1;
  const int l = (h << 5) | (row & 31);
  *(uint2*)(dst + (size_t)(row >> 5) * 16384 + pp * 1024 + l * 16 + sub * 8) = o;
  ss += __shfl_xor(ss, 1);  ss += __shfl_xor(ss, 2);
  ss += __shfl_xor(ss, 4);  ss += __shfl_xor(ss, 8);
  ss += __shfl_xor(ss, 16); ss += __shfl_xor(ss, 32);
  if (i6 == 0) sq[row] = ss;
}

// ---------- prep: centers -> fp8 frag-stream [chunk(128)][p(16)][cgrp(4)][swz unit(16)]16B + csq ----------
// read addr (lane c=l&31,h=l>>5): p*1024 + (c>>3)*256 + ((((c&7)*2+h)^((c>>2)&1)))*16
__global__ __launch_bounds__(256)
void prep_cen(const float* __restrict__ cen, u8* __restrict__ cfr,
              float* __restrict__ csq) {
  const int t = threadIdx.x;
  const int c = blockIdx.x * 4 + (t >> 6);
  const int i6 = t & 63;
  const float* p = cen + (size_t)c * 512 + i6 * 8;
  float4 a = *(const float4*)p, b = *(const float4*)(p + 4);
  float ss = a.x*a.x + a.y*a.y + a.z*a.z + a.w*a.w
           + b.x*b.x + b.y*b.y + b.z*b.z + b.w*b.w;
  uint2 o;
  o.x = pk4(a.x, a.y, a.z, a.w);
  o.y = pk4(b.x, b.y, b.z, b.w);
  const int pp = i6 >> 2, sub = (i6 >> 1) & 1, h = i6 & 1;
  const int lc = c & 31;
  const int v = (((lc & 7) * 2 + h) ^ ((lc >> 2) & 1));
  *(uint2*)(cfr + (size_t)(c >> 5) * 16384 + pp * 1024 + (lc >> 3) * 256
            + v * 16 + sub * 8) = o;
  ss += __shfl_xor(ss, 1);  ss += __shfl_xor(ss, 2);
  ss += __shfl_xor(ss, 4);  ss += __shfl_xor(ss, 8);
  ss += __shfl_xor(ss, 16); ss += __shfl_xor(ss, 32);
  if (i6 == 0) csq[c] = ss;
}

// ---------- prep: W [4096][128] f32 -> chunk-major bf16 units ----------
// element (o,c): byte = (c>>5)*8192 + o*64 + (((((c&31)>>4)*2 + ((c>>3)&1)) ^ ((o>>1)&3)))*16 + (c&7)*2
__global__ __launch_bounds__(256)
void prep_w(const float* __restrict__ W, u8* __restrict__ wt) {
  __shared__ u16 t_[128 * 66];
  const int c0 = blockIdx.x * 64;
  const int t = threadIdx.x;
#pragma unroll
  for (int it = 0; it < 32; ++it) {
    int idx = it * 256 + t;
    int cl = idx >> 7;
    int o  = idx & 127;
    t_[o * 66 + cl] = f2bf(W[(size_t)(c0 + cl) * 128 + o]);
  }
  __syncthreads();
#pragma unroll
  for (int it = 0; it < 4; ++it) {
    int idx = it * 256 + t;            // 0..1023 : 16B units
    int o  = idx >> 3;
    int uu = idx & 7;
    int ch = uu >> 2;                  // local chunk 0/1
    int kt = (uu >> 1) & 1;
    int h2 = uu & 1;
    int u  = (kt * 2 + h2) ^ ((o >> 1) & 3);
    u16* d = (u16*)(wt + ((size_t)(c0 >> 5) + ch) * 8192 + o * 64 + u * 16);
    const u16* s_ = &t_[o * 66 + ch * 32 + kt * 16 + h2 * 8];
#pragma unroll
    for (int j = 0; j < 8; ++j) d[j] = s_[j];
  }
}

// ---------- init: out = bias ----------
__global__ __launch_bounds__(256)
void init_out(const float* __restrict__ bias, float* __restrict__ out) {
  const int i4 = blockIdx.x * 256 + threadIdx.x;
  float4 b = ((const float4*)bias)[i4 & 31];
  ((float4*)out)[i4] = b;
}

// ---------- main: 512 blocks(256thr) = 128 row-tiles(128r) x 4 quarters ----------
// 4 waves x 32 rows; 32x32x16 MFMAs; P fully in-register via cvt_pk + permlane32_swap.
__global__ __launch_bounds__(256, 2)
void rbf_main(const u8* __restrict__ xfs, const u8* __restrict__ cfr,
              const u8* __restrict__ wtgb, const float* __restrict__ csq_g,
              const float* __restrict__ xsq_g, float* __restrict__ out)
{
  __shared__ __align__(16) u8 cs[2][16384];   // center chunk dbuf (32c x 512k fp8 stream)
  __shared__ __align__(16) u8 wt[2][8192];    // W chunk dbuf [128o][32c] bf16 units
  __shared__ __align__(16) float csq_l[1024];
  __shared__ __align__(16) float xsq_l[128];

  const int tid = threadIdx.x;
  const int lane = tid & 63;
  const int wv = tid >> 6;                 // wave 0..3 -> rows wv*32..+32
  const int l31 = lane & 31;
  const int h = lane >> 5;
  const int bid = blockIdx.x;
  const int chq = bid & 3;
  const size_t r0 = (size_t)(bid >> 2) * 128;

#define S_CS(cc) do { \
    const u8* sG_ = cfr + ((size_t)(chq * 32 + (cc)) << 14) + tid * 16; \
    u8* sL_ = &cs[(cc) & 1][0] + tid * 16; \
    GLOAD_LDS(sG_,         sL_); \
    GLOAD_LDS(sG_ + 4096,  sL_ + 4096); \
    GLOAD_LDS(sG_ + 8192,  sL_ + 8192); \
    GLOAD_LDS(sG_ + 12288, sL_ + 12288); \
  } while (0)

#define S_W(cc) do { \
    const u8* wg_ = wtgb + ((size_t)(chq * 32 + (cc)) << 13) + tid * 16; \
    u8* wl_ = &wt[(cc) & 1][0] + tid * 16; \
    GLOAD_LDS(wg_,        wl_); \
    GLOAD_LDS(wg_ + 4096, wl_ + 4096); \
  } while (0)

  // prologue staging
  if (tid < 32) GLOAD_LDS(xsq_g + r0 + tid * 4, xsq_l + tid * 4);
  GLOAD_LDS(csq_g + chq * 1024 + tid * 4, csq_l + tid * 4);
  S_CS(0);
  S_W(0);

  // x fragments: 16 x b128 coalesced from frag-stream
  l64x2 xf[16];
  {
    const u8* xb = xfs + ((size_t)((bid >> 2) * 4 + wv)) * 16384 + lane * 16;
#pragma unroll
    for (int p = 0; p < 16; ++p)
      xf[p] = *(const l64x2*)(xb + p * 1024);
  }

  asm volatile("s_waitcnt vmcnt(0)" ::: "memory");
  __builtin_amdgcn_s_barrier();
  __builtin_amdgcn_sched_barrier(0);

  const float xn = NB2 * xsq_l[wv * 32 + l31];

  // LDS read bases (octet-distinct bank quads by construction)
  const int cbase = ((l31 >> 3) & 3) * 256
                  + ((((l31 & 7) * 2 + h) ^ ((l31 >> 2) & 1)) << 4);
  const int wsw = (l31 >> 1) & 3;
  const int wb_o = l31 * 64;
  const int wu0 = ((0 + h) ^ wsw) << 4;   // kt=0
  const int wu1 = ((2 + h) ^ wsw) << 4;   // kt=1

  const f32x16 z16 = {0,0,0,0,0,0,0,0,0,0,0,0,0,0,0,0};
  f32x16 oa0 = z16, oa1 = z16, oa2 = z16, oa3 = z16;

#pragma unroll 1
  for (int cc = 0; cc < 32; ++cc) {
    if (cc < 31) { S_CS(cc + 1); S_W(cc + 1); }
    const u8* csb = &cs[cc & 1][0];

    // ---- GEMM1 (swapped): D[c][m]; A=centers(LDS), B=x(regs); split-K 2 chains ----
    f32x16 s0 = z16, s1 = z16;
#pragma unroll
    for (int p = 0; p < 16; ++p) {
      l64x2 A = *(const l64x2*)(csb + p * 1024 + cbase);
      __builtin_amdgcn_s_setprio(1);
      if (p & 1) {
        s1 = MF8(A[0], xf[p][0], s1);
        s1 = MF8(A[1], xf[p][1], s1);
      } else {
        s0 = MF8(A[0], xf[p][0], s0);
        s0 = MF8(A[1], xf[p][1], s0);
      }
      __builtin_amdgcn_s_setprio(0);
    }

    // ---- rbf in registers: lane m=l31; reg r -> c = (r&3) + 8*(r>>2) + 4*h ----
    f32x4 cq0 = *(const f32x4*)(csq_l + cc * 32 + 0  + 4 * h);
    f32x4 cq1 = *(const f32x4*)(csq_l + cc * 32 + 8  + 4 * h);
    f32x4 cq2 = *(const f32x4*)(csq_l + cc * 32 + 16 + 4 * h);
    f32x4 cq3 = *(const f32x4*)(csq_l + cc * 32 + 24 + 4 * h);
    float e[16];
#pragma unroll
    for (int r = 0; r < 16; ++r) {
      const float cq = (r < 4 ? cq0[r] : r < 8 ? cq1[r - 4] : r < 12 ? cq2[r - 8] : cq3[r - 12]);
      e[r] = __builtin_amdgcn_exp2f(fmaf(s0[r] + s1[r], P2C, fmaf(cq, NB2, xn)));
    }
    // pack pairs (c, c+1) then half-exchange -> GEMM2 A-frags
    unsigned P0 = cvtpk(e[0],  e[1]),  P1 = cvtpk(e[2],  e[3]);
    unsigned P2 = cvtpk(e[4],  e[5]),  P3 = cvtpk(e[6],  e[7]);
    unsigned P4 = cvtpk(e[8],  e[9]),  P5 = cvtpk(e[10], e[11]);
    unsigned P6 = cvtpk(e[12], e[13]), P7 = cvtpk(e[14], e[15]);
    pswap(P0, P2); pswap(P1, P3);      // F: c 0..15   (F0=P0,F1=P1,F2=P2,F3=P3)
    pswap(P4, P6); pswap(P5, P7);      // G: c 16..31
    union { unsigned u[4]; bf16x8 v; } FA, GA;
    FA.u[0] = P0; FA.u[1] = P1; FA.u[2] = P2; FA.u[3] = P3;
    GA.u[0] = P4; GA.u[1] = P5; GA.u[2] = P6; GA.u[3] = P7;

    // ---- GEMM2: D[m][o] += P(32m x 32c) x W(32c x 128o) ----
    {
      const u8* wtb = &wt[cc & 1][0];
      bf16x8 wA0 = *(const bf16x8*)(wtb + wb_o + wu0);
      bf16x8 wB0 = *(const bf16x8*)(wtb + wb_o + wu1);
      bf16x8 wA1 = *(const bf16x8*)(wtb + 2048 + wb_o + wu0);
      bf16x8 wB1 = *(const bf16x8*)(wtb + 2048 + wb_o + wu1);
      __builtin_amdgcn_s_setprio(1);
      oa0 = MFB(FA.v, wA0, oa0);
      oa0 = MFB(GA.v, wB0, oa0);
      oa1 = MFB(FA.v, wA1, oa1);
      oa1 = MFB(GA.v, wB1, oa1);
      __builtin_amdgcn_s_setprio(0);
      bf16x8 wA2 = *(const bf16x8*)(wtb + 4096 + wb_o + wu0);
      bf16x8 wB2 = *(const bf16x8*)(wtb + 4096 + wb_o + wu1);
      bf16x8 wA3 = *(const bf16x8*)(wtb + 6144 + wb_o + wu0);
      bf16x8 wB3 = *(const bf16x8*)(wtb + 6144 + wb_o + wu1);
      __builtin_amdgcn_s_setprio(1);
      oa2 = MFB(FA.v, wA2, oa2);
      oa2 = MFB(GA.v, wB2, oa2);
      oa3 = MFB(FA.v, wA3, oa3);
      oa3 = MFB(GA.v, wB3, oa3);
      __builtin_amdgcn_s_setprio(0);
    }

    asm volatile("s_waitcnt vmcnt(0)" ::: "memory");
    __builtin_amdgcn_s_barrier();
    __builtin_amdgcn_sched_barrier(0);
  }

  // epilogue: out += partial; D rows m=(r&3)+8*(r>>2)+4h, cols o=t*32+l31
#pragma unroll
  for (int r = 0; r < 16; ++r) {
    const int m = wv * 32 + (r & 3) + 8 * (r >> 2) + 4 * h;
    float* op = &out[(r0 + m) * 128 + l31];
    atomicAdd(op,      oa0[r]);
    atomicAdd(op + 32, oa1[r]);
    atomicAdd(op + 64, oa2[r]);
    atomicAdd(op + 96, oa3[r]);
  }
#undef S_CS
#undef S_W
}

extern "C" void kernel_launch(void* const* d_in, const int* in_sizes, int n_in,
                              void* d_out, int out_size, void* d_ws, size_t ws_size,
                              hipStream_t stream) {
  (void)in_sizes; (void)n_in; (void)out_size; (void)ws_size;
  const float* x   = (const float*)d_in[0];
  const float* cen = (const float*)d_in[1];
  const float* W   = (const float*)d_in[2];
  const float* b   = (const float*)d_in[3];
  u8* xfs = (u8*)d_ws;                          // 16384*512 = 8 MB (x frag-stream)
  u8* cfr = xfs + (size_t)16384 * 512;          // 4096*512  = 2 MB (center frag-stream)
  u8* wtgb = cfr + (size_t)4096 * 512;          // 1 MB (W chunk-major units)
  float* csq = (float*)(wtgb + (size_t)128 * 4096 * 2);  // 16 KB
  float* xsq = csq + 4096;                      // 64 KB
  prep_x8<<<2048, 512, 0, stream>>>(x, xfs, xsq);
  prep_cen<<<1024, 256, 0, stream>>>(cen, cfr, csq);
  prep_w<<<64, 256, 0, stream>>>(W, wtgb);
  init_out<<<2048, 256, 0, stream>>>(b, (float*)d_out);
  rbf_main<<<512, 256, 0, stream>>>(xfs, cfr, wtgb, csq, xsq, (float*)d_out);
}

// Round 18
// 93.508 us; speedup vs baseline: 1.2229x; 1.1334x over previous
//
#include <hip/hip_runtime.h>
#include <hip/hip_bf16.h>

typedef short bf16x8 __attribute__((ext_vector_type(8)));
typedef float f32x4 __attribute__((ext_vector_type(4)));
typedef float f32x16 __attribute__((ext_vector_type(16)));
typedef long l64x2 __attribute__((ext_vector_type(2)));
typedef int i32x8 __attribute__((ext_vector_type(8)));
typedef unsigned short u16;
typedef unsigned char u8;

#define NB2 (-0.35f * 1.44269504088896340736f)
#define P2C (0.70f * 1.44269504088896340736f)
// MX-scaled fp8 e4m3 (cbsz=0, blgp=0), all scales = 1.0 (E8M0 127)
#define MFS(a,b,c) __builtin_amdgcn_mfma_scale_f32_32x32x64_f8f6f4( \
    a, b, c, 0, 0, 0, 0x7F7F7F7F, 0, 0x7F7F7F7F)
#define MFB(a,b,c) __builtin_amdgcn_mfma_f32_32x32x16_bf16(a, b, c, 0, 0, 0)

__device__ __forceinline__ u16 f2bf(float f) {
  union { float f; unsigned int u; } v; v.f = f;
  unsigned int x = v.u;
  return (u16)((x + 0x7FFFu + ((x >> 16) & 1u)) >> 16);
}

__device__ __forceinline__ unsigned cvtpk(float lo, float hi) {
  unsigned r;
  asm("v_cvt_pk_bf16_f32 %0, %1, %2" : "=v"(r) : "v"(lo), "v"(hi));
  return r;
}

__device__ __forceinline__ void pswap(unsigned &a, unsigned &b) {
  asm volatile("v_permlane32_swap_b32 %0, %1" : "+v"(a), "+v"(b));
}

__device__ __forceinline__ u8 f2e4m3(float f) {
  unsigned int u = __float_as_uint(f);
  u8 s = (u8)((u >> 24) & 0x80u);
  float a = fabsf(f);
  if (a >= 448.f) return s | 0x7E;
  if (a < 0.015625f) return s | (u8)(int)rintf(a * 512.f);
  unsigned int m = u & 0x7fffffffu;
  unsigned int r = m + 0x7FFFFu + ((m >> 20) & 1u);
  return s | (u8)((((r >> 23) - 120u) << 3) | ((r >> 20) & 7u));
}

__device__ __forceinline__ unsigned int pk4(float a, float b, float c, float d) {
#if __has_builtin(__builtin_amdgcn_cvt_pk_fp8_f32)
  int v = __builtin_amdgcn_cvt_pk_fp8_f32(a, b, 0, false);
  v = __builtin_amdgcn_cvt_pk_fp8_f32(c, d, v, true);
  return (unsigned int)v;
#else
  return (unsigned int)f2e4m3(a) | ((unsigned int)f2e4m3(b) << 8)
       | ((unsigned int)f2e4m3(c) << 16) | ((unsigned int)f2e4m3(d) << 24);
#endif
}

#define GLOAD_LDS(g, l) __builtin_amdgcn_global_load_lds( \
    (const __attribute__((address_space(1))) unsigned int*)(g), \
    (__attribute__((address_space(3))) unsigned int*)(l), 16, 0, 0)

// ---------- prep: x -> fp8 K=64 frag-stream [tile32][P(8)][lane(64)][32B] + xsq ----------
// lane l = (khalf<<5)|(row&31); bytes b: k = P*64 + khalf*32 + b (linear, no swizzle)
__global__ __launch_bounds__(512)
void prep_x8(const float* __restrict__ src, u8* __restrict__ dst,
             float* __restrict__ sq) {
  const int row = blockIdx.x * 8 + (threadIdx.x >> 6);
  const int i6 = threadIdx.x & 63;            // k-granule: k in [i6*8, i6*8+8)
  const float4* p = (const float4*)(src + (size_t)row * 512) + i6 * 2;
  float4 a = p[0], b = p[1];
  float ss = a.x*a.x + a.y*a.y + a.z*a.z + a.w*a.w
           + b.x*b.x + b.y*b.y + b.z*b.z + b.w*b.w;
  uint2 o;
  o.x = pk4(a.x, a.y, a.z, a.w);
  o.y = pk4(b.x, b.y, b.z, b.w);
  const int P = i6 >> 3, rem = i6 & 7;
  const int kh = rem >> 2;
  const int l = (kh << 5) | (row & 31);
  *(uint2*)(dst + (size_t)(row >> 5) * 16384 + P * 2048 + l * 32 + (rem & 3) * 8) = o;
  ss += __shfl_xor(ss, 1);  ss += __shfl_xor(ss, 2);
  ss += __shfl_xor(ss, 4);  ss += __shfl_xor(ss, 8);
  ss += __shfl_xor(ss, 16); ss += __shfl_xor(ss, 32);
  if (i6 == 0) sq[row] = ss;
}

// ---------- prep: centers -> fp8 K=64 frag-stream with 16B-unit XOR swizzle + csq ----------
// stored unit us = u ^ ((c>>2)&1); read: lane l, s=(l>>2)&1, lo at +s*16, hi at +(s^1)*16
__global__ __launch_bounds__(256)
void prep_cen(const float* __restrict__ cen, u8* __restrict__ cfr,
              float* __restrict__ csq) {
  const int t = threadIdx.x;
  const int c = blockIdx.x * 4 + (t >> 6);
  const int i6 = t & 63;
  const float* p = cen + (size_t)c * 512 + i6 * 8;
  float4 a = *(const float4*)p, b = *(const float4*)(p + 4);
  float ss = a.x*a.x + a.y*a.y + a.z*a.z + a.w*a.w
           + b.x*b.x + b.y*b.y + b.z*b.z + b.w*b.w;
  uint2 o;
  o.x = pk4(a.x, a.y, a.z, a.w);
  o.y = pk4(b.x, b.y, b.z, b.w);
  const int P = i6 >> 3, rem = i6 & 7;
  const int kh = rem >> 2;
  const int lc = c & 31;
  const int l = (kh << 5) | lc;
  const int u = (rem >> 1) & 1;
  const int sub = rem & 1;
  const int us = u ^ ((lc >> 2) & 1);
  *(uint2*)(cfr + (size_t)(c >> 5) * 16384 + P * 2048 + l * 32 + us * 16 + sub * 8) = o;
  ss += __shfl_xor(ss, 1);  ss += __shfl_xor(ss, 2);
  ss += __shfl_xor(ss, 4);  ss += __shfl_xor(ss, 8);
  ss += __shfl_xor(ss, 16); ss += __shfl_xor(ss, 32);
  if (i6 == 0) csq[c] = ss;
}

// ---------- prep: W [4096][128] f32 -> chunk-major bf16 units (unchanged from R11) ----------
__global__ __launch_bounds__(256)
void prep_w(const float* __restrict__ W, u8* __restrict__ wt) {
  __shared__ u16 t_[128 * 66];
  const int c0 = blockIdx.x * 64;
  const int t = threadIdx.x;
#pragma unroll
  for (int it = 0; it < 32; ++it) {
    int idx = it * 256 + t;
    int cl = idx >> 7;
    int o  = idx & 127;
    t_[o * 66 + cl] = f2bf(W[(size_t)(c0 + cl) * 128 + o]);
  }
  __syncthreads();
#pragma unroll
  for (int it = 0; it < 4; ++it) {
    int idx = it * 256 + t;            // 0..1023 : 16B units
    int o  = idx >> 3;
    int uu = idx & 7;
    int ch = uu >> 2;                  // local chunk 0/1
    int kt = (uu >> 1) & 1;
    int h2 = uu & 1;
    int u  = (kt * 2 + h2) ^ ((o >> 1) & 3);
    u16* d = (u16*)(wt + ((size_t)(c0 >> 5) + ch) * 8192 + o * 64 + u * 16);
    const u16* s_ = &t_[o * 66 + ch * 32 + kt * 16 + h2 * 8];
#pragma unroll
    for (int j = 0; j < 8; ++j) d[j] = s_[j];
  }
}

// ---------- init: out = bias ----------
__global__ __launch_bounds__(256)
void init_out(const float* __restrict__ bias, float* __restrict__ out) {
  const int i4 = blockIdx.x * 256 + threadIdx.x;
  float4 b = ((const float4*)bias)[i4 & 31];
  ((float4*)out)[i4] = b;
}

// ---------- main: 512 blocks(256thr) = 128 row-tiles(128r) x 4 quarters ----------
// R11 skeleton; GEMM1 = 8 x MX-scaled 32x32x64 fp8 (scales=1.0) instead of 32 x 32x32x16.
__global__ __launch_bounds__(256, 2)
void rbf_main(const u8* __restrict__ xfs, const u8* __restrict__ cfr,
              const u8* __restrict__ wtgb, const float* __restrict__ csq_g,
              const float* __restrict__ xsq_g, float* __restrict__ out)
{
  __shared__ __align__(16) u8 cs[2][16384];   // center chunk dbuf (32c x 512k fp8 stream)
  __shared__ __align__(16) u8 wt[2][8192];    // W chunk dbuf [128o][32c] bf16 units
  __shared__ __align__(16) float csq_l[1024];
  __shared__ __align__(16) float xsq_l[128];

  const int tid = threadIdx.x;
  const int lane = tid & 63;
  const int wv = tid >> 6;                 // wave 0..3 -> rows wv*32..+32
  const int l31 = lane & 31;
  const int h = lane >> 5;
  const int bid = blockIdx.x;
  const int chq = bid & 3;
  const size_t r0 = (size_t)(bid >> 2) * 128;

#define S_CS(cc) do { \
    const u8* sG_ = cfr + ((size_t)(chq * 32 + (cc)) << 14) + tid * 16; \
    u8* sL_ = &cs[(cc) & 1][0] + tid * 16; \
    GLOAD_LDS(sG_,         sL_); \
    GLOAD_LDS(sG_ + 4096,  sL_ + 4096); \
    GLOAD_LDS(sG_ + 8192,  sL_ + 8192); \
    GLOAD_LDS(sG_ + 12288, sL_ + 12288); \
  } while (0)

#define S_W(cc) do { \
    const u8* wg_ = wtgb + ((size_t)(chq * 32 + (cc)) << 13) + tid * 16; \
    u8* wl_ = &wt[(cc) & 1][0] + tid * 16; \
    GLOAD_LDS(wg_,        wl_); \
    GLOAD_LDS(wg_ + 4096, wl_ + 4096); \
  } while (0)

  // prologue staging
  if (tid < 32) GLOAD_LDS(xsq_g + r0 + tid * 4, xsq_l + tid * 4);
  GLOAD_LDS(csq_g + chq * 1024 + tid * 4, csq_l + tid * 4);
  S_CS(0);
  S_W(0);

  // x fragments: 8 x 32B (K=64 each) from frag-stream
  i32x8 xf8[8];
  {
    const u8* xb = xfs + ((size_t)((bid >> 2) * 4 + wv)) * 16384 + lane * 32;
#pragma unroll
    for (int P = 0; P < 8; ++P) {
      union { l64x2 q[2]; i32x8 v; } t;
      t.q[0] = *(const l64x2*)(xb + P * 2048);
      t.q[1] = *(const l64x2*)(xb + P * 2048 + 16);
      xf8[P] = t.v;
    }
  }

  asm volatile("s_waitcnt vmcnt(0)" ::: "memory");
  __builtin_amdgcn_s_barrier();
  __builtin_amdgcn_sched_barrier(0);

  const float xn = NB2 * xsq_l[wv * 32 + l31];

  // LDS read bases (octet-distinct bank quads by construction)
  const int swz = (lane >> 2) & 1;
  const int alo = lane * 32 + swz * 16;        // logical k-bytes 0..15
  const int ahi = lane * 32 + (swz ^ 1) * 16;  // logical k-bytes 16..31
  const int wsw = (l31 >> 1) & 3;
  const int wb_o = l31 * 64;
  const int wu0 = ((0 + h) ^ wsw) << 4;   // kt=0
  const int wu1 = ((2 + h) ^ wsw) << 4;   // kt=1

  const f32x16 z16 = {0,0,0,0,0,0,0,0,0,0,0,0,0,0,0,0};
  f32x16 oa0 = z16, oa1 = z16, oa2 = z16, oa3 = z16;

#pragma unroll 1
  for (int cc = 0; cc < 32; ++cc) {
    if (cc < 31) { S_CS(cc + 1); S_W(cc + 1); }
    const u8* csb = &cs[cc & 1][0];

    // ---- GEMM1 (swapped, MX): D[c][m]; A=centers(LDS), B=x(regs); 2 chains ----
    f32x16 s0 = z16, s1 = z16;
#pragma unroll
    for (int P = 0; P < 8; ++P) {
      union { l64x2 q[2]; i32x8 v; } A;
      A.q[0] = *(const l64x2*)(csb + P * 2048 + alo);
      A.q[1] = *(const l64x2*)(csb + P * 2048 + ahi);
      __builtin_amdgcn_s_setprio(1);
      if (P & 1) s1 = MFS(A.v, xf8[P], s1);
      else       s0 = MFS(A.v, xf8[P], s0);
      __builtin_amdgcn_s_setprio(0);
    }

    // ---- rbf in registers: lane m=l31; reg r -> c = (r&3) + 8*(r>>2) + 4*h ----
    f32x4 cq0 = *(const f32x4*)(csq_l + cc * 32 + 0  + 4 * h);
    f32x4 cq1 = *(const f32x4*)(csq_l + cc * 32 + 8  + 4 * h);
    f32x4 cq2 = *(const f32x4*)(csq_l + cc * 32 + 16 + 4 * h);
    f32x4 cq3 = *(const f32x4*)(csq_l + cc * 32 + 24 + 4 * h);
    float e[16];
#pragma unroll
    for (int r = 0; r < 16; ++r) {
      const float cq = (r < 4 ? cq0[r] : r < 8 ? cq1[r - 4] : r < 12 ? cq2[r - 8] : cq3[r - 12]);
      e[r] = __builtin_amdgcn_exp2f(fmaf(s0[r] + s1[r], P2C, fmaf(cq, NB2, xn)));
    }
    // pack pairs (c, c+1) then half-exchange -> GEMM2 A-frags
    unsigned P0 = cvtpk(e[0],  e[1]),  P1 = cvtpk(e[2],  e[3]);
    unsigned P2 = cvtpk(e[4],  e[5]),  P3 = cvtpk(e[6],  e[7]);
    unsigned P4 = cvtpk(e[8],  e[9]),  P5 = cvtpk(e[10], e[11]);
    unsigned P6 = cvtpk(e[12], e[13]), P7 = cvtpk(e[14], e[15]);
    pswap(P0, P2); pswap(P1, P3);      // F: c 0..15
    pswap(P4, P6); pswap(P5, P7);      // G: c 16..31
    union { unsigned u[4]; bf16x8 v; } FA, GA;
    FA.u[0] = P0; FA.u[1] = P1; FA.u[2] = P2; FA.u[3] = P3;
    GA.u[0] = P4; GA.u[1] = P5; GA.u[2] = P6; GA.u[3] = P7;

    // ---- GEMM2: D[m][o] += P(32m x 32c) x W(32c x 128o) ----
    {
      const u8* wtb = &wt[cc & 1][0];
      bf16x8 wA0 = *(const bf16x8*)(wtb + wb_o + wu0);
      bf16x8 wB0 = *(const bf16x8*)(wtb + wb_o + wu1);
      bf16x8 wA1 = *(const bf16x8*)(wtb + 2048 + wb_o + wu0);
      bf16x8 wB1 = *(const bf16x8*)(wtb + 2048 + wb_o + wu1);
      __builtin_amdgcn_s_setprio(1);
      oa0 = MFB(FA.v, wA0, oa0);
      oa0 = MFB(GA.v, wB0, oa0);
      oa1 = MFB(FA.v, wA1, oa1);
      oa1 = MFB(GA.v, wB1, oa1);
      __builtin_amdgcn_s_setprio(0);
      bf16x8 wA2 = *(const bf16x8*)(wtb + 4096 + wb_o + wu0);
      bf16x8 wB2 = *(const bf16x8*)(wtb + 4096 + wb_o + wu1);
      bf16x8 wA3 = *(const bf16x8*)(wtb + 6144 + wb_o + wu0);
      bf16x8 wB3 = *(const bf16x8*)(wtb + 6144 + wb_o + wu1);
      __builtin_amdgcn_s_setprio(1);
      oa2 = MFB(FA.v, wA2, oa2);
      oa2 = MFB(GA.v, wB2, oa2);
      oa3 = MFB(FA.v, wA3, oa3);
      oa3 = MFB(GA.v, wB3, oa3);
      __builtin_amdgcn_s_setprio(0);
    }

    asm volatile("s_waitcnt vmcnt(0)" ::: "memory");
    __builtin_amdgcn_s_barrier();
    __builtin_amdgcn_sched_barrier(0);
  }

  // epilogue: out += partial; D rows m=(r&3)+8*(r>>2)+4h, cols o=ot*32+l31
#pragma unroll
  for (int r = 0; r < 16; ++r) {
    const int m = wv * 32 + (r & 3) + 8 * (r >> 2) + 4 * h;
    float* op = &out[(r0 + m) * 128 + l31];
    atomicAdd(op,      oa0[r]);
    atomicAdd(op + 32, oa1[r]);
    atomicAdd(op + 64, oa2[r]);
    atomicAdd(op + 96, oa3[r]);
  }
#undef S_CS
#undef S_W
}

extern "C" void kernel_launch(void* const* d_in, const int* in_sizes, int n_in,
                              void* d_out, int out_size, void* d_ws, size_t ws_size,
                              hipStream_t stream) {
  (void)in_sizes; (void)n_in; (void)out_size; (void)ws_size;
  const float* x   = (const float*)d_in[0];
  const float* cen = (const float*)d_in[1];
  const float* W   = (const float*)d_in[2];
  const float* b   = (const float*)d_in[3];
  u8* xfs = (u8*)d_ws;                          // 8 MB (x K=64 frag-stream)
  u8* cfr = xfs + (size_t)16384 * 512;          // 2 MB (center K=64 frag-stream)
  u8* wtgb = cfr + (size_t)4096 * 512;          // 1 MB (W chunk-major units)
  float* csq = (float*)(wtgb + (size_t)128 * 4096 * 2);  // 16 KB
  float* xsq = csq + 4096;                      // 64 KB
  prep_x8<<<2048, 512, 0, stream>>>(x, xfs, xsq);
  prep_cen<<<1024, 256, 0, stream>>>(cen, cfr, csq);
  prep_w<<<64, 256, 0, stream>>>(W, wtgb);
  init_out<<<2048, 256, 0, stream>>>(b, (float*)d_out);
  rbf_main<<<512, 256, 0, stream>>>(xfs, cfr, wtgb, csq, xsq, (float*)d_out);
}

// Round 19
// 87.978 us; speedup vs baseline: 1.2998x; 1.0629x over previous
//
#include <hip/hip_runtime.h>
#include <hip/hip_bf16.h>

typedef float f32x4 __attribute__((ext_vector_type(4)));
typedef float f32x16 __attribute__((ext_vector_type(16)));
typedef long l64x2 __attribute__((ext_vector_type(2)));
typedef int i32x8 __attribute__((ext_vector_type(8)));
typedef unsigned short u16;
typedef unsigned char u8;

#define NB2 (-0.35f * 1.44269504088896340736f)
#define P2C (0.70f * 1.44269504088896340736f)
// MX-scaled fp8 e4m3 (cbsz=0, blgp=0), scales 1.0
#define MFS(a,b,c) __builtin_amdgcn_mfma_scale_f32_32x32x64_f8f6f4( \
    a, b, c, 0, 0, 0, 0x7F7F7F7F, 0, 0x7F7F7F7F)
// GEMM2: A=P (scale 1.0), B=W stored x64 (scale 2^-6 = E8M0 121 = 0x79)
#define MFS2(a,b,c) __builtin_amdgcn_mfma_scale_f32_32x32x64_f8f6f4( \
    a, b, c, 0, 0, 0, 0x7F7F7F7F, 0, 0x79797979)

__device__ __forceinline__ void pswap(unsigned &a, unsigned &b) {
  asm volatile("v_permlane32_swap_b32 %0, %1" : "+v"(a), "+v"(b));
}

__device__ __forceinline__ u8 f2e4m3(float f) {
  unsigned int u = __float_as_uint(f);
  u8 s = (u8)((u >> 24) & 0x80u);
  float a = fabsf(f);
  if (a >= 448.f) return s | 0x7E;
  if (a < 0.015625f) return s | (u8)(int)rintf(a * 512.f);
  unsigned int m = u & 0x7fffffffu;
  unsigned int r = m + 0x7FFFFu + ((m >> 20) & 1u);
  return s | (u8)((((r >> 23) - 120u) << 3) | ((r >> 20) & 7u));
}

__device__ __forceinline__ unsigned int pk4(float a, float b, float c, float d) {
#if __has_builtin(__builtin_amdgcn_cvt_pk_fp8_f32)
  int v = __builtin_amdgcn_cvt_pk_fp8_f32(a, b, 0, false);
  v = __builtin_amdgcn_cvt_pk_fp8_f32(c, d, v, true);
  return (unsigned int)v;
#else
  return (unsigned int)f2e4m3(a) | ((unsigned int)f2e4m3(b) << 8)
       | ((unsigned int)f2e4m3(c) << 16) | ((unsigned int)f2e4m3(d) << 24);
#endif
}

#define GLOAD_LDS(g, l) __builtin_amdgcn_global_load_lds( \
    (const __attribute__((address_space(1))) unsigned int*)(g), \
    (__attribute__((address_space(3))) unsigned int*)(l), 16, 0, 0)

// ---------- prep: x -> fp8 K=64 frag-stream [tile32][P(8)][lane(64)][32B] + xsq ----------
__global__ __launch_bounds__(512)
void prep_x8(const float* __restrict__ src, u8* __restrict__ dst,
             float* __restrict__ sq) {
  const int row = blockIdx.x * 8 + (threadIdx.x >> 6);
  const int i6 = threadIdx.x & 63;
  const float4* p = (const float4*)(src + (size_t)row * 512) + i6 * 2;
  float4 a = p[0], b = p[1];
  float ss = a.x*a.x + a.y*a.y + a.z*a.z + a.w*a.w
           + b.x*b.x + b.y*b.y + b.z*b.z + b.w*b.w;
  uint2 o;
  o.x = pk4(a.x, a.y, a.z, a.w);
  o.y = pk4(b.x, b.y, b.z, b.w);
  const int P = i6 >> 3, rem = i6 & 7;
  const int kh = rem >> 2;
  const int l = (kh << 5) | (row & 31);
  *(uint2*)(dst + (size_t)(row >> 5) * 16384 + P * 2048 + l * 32 + (rem & 3) * 8) = o;
  ss += __shfl_xor(ss, 1);  ss += __shfl_xor(ss, 2);
  ss += __shfl_xor(ss, 4);  ss += __shfl_xor(ss, 8);
  ss += __shfl_xor(ss, 16); ss += __shfl_xor(ss, 32);
  if (i6 == 0) sq[row] = ss;
}

// ---------- prep: centers -> fp8 K=64 frag-stream with 16B-unit XOR swizzle + csq ----------
__global__ __launch_bounds__(256)
void prep_cen(const float* __restrict__ cen, u8* __restrict__ cfr,
              float* __restrict__ csq) {
  const int t = threadIdx.x;
  const int c = blockIdx.x * 4 + (t >> 6);
  const int i6 = t & 63;
  const float* p = cen + (size_t)c * 512 + i6 * 8;
  float4 a = *(const float4*)p, b = *(const float4*)(p + 4);
  float ss = a.x*a.x + a.y*a.y + a.z*a.z + a.w*a.w
           + b.x*b.x + b.y*b.y + b.z*b.z + b.w*b.w;
  uint2 o;
  o.x = pk4(a.x, a.y, a.z, a.w);
  o.y = pk4(b.x, b.y, b.z, b.w);
  const int P = i6 >> 3, rem = i6 & 7;
  const int kh = rem >> 2;
  const int lc = c & 31;
  const int l = (kh << 5) | lc;
  const int u = (rem >> 1) & 1;
  const int sub = rem & 1;
  const int us = u ^ ((lc >> 2) & 1);
  *(uint2*)(cfr + (size_t)(c >> 5) * 16384 + P * 2048 + l * 32 + us * 16 + sub * 8) = o;
  ss += __shfl_xor(ss, 1);  ss += __shfl_xor(ss, 2);
  ss += __shfl_xor(ss, 4);  ss += __shfl_xor(ss, 8);
  ss += __shfl_xor(ss, 16); ss += __shfl_xor(ss, 32);
  if (i6 == 0) csq[c] = ss;
}

// ---------- prep: W [4096][128] f32 -> fp8(x64) MX B-operand pair-stream ----------
// wfr[pair*8192 + ot*2048 + l*32 + b] = e4m3(64 * W[pair*64 + (l>>5)*32 + b][ot*32 + (l&31)])
__global__ __launch_bounds__(256)
void prep_w(const float* __restrict__ W, u8* __restrict__ wfr) {
  __shared__ float t_[64 * 128];   // 32 KB
  const int pr = blockIdx.x;       // pair 0..63
  const int t = threadIdx.x;
#pragma unroll
  for (int it = 0; it < 32; ++it) {
    int idx = it * 256 + t;        // 0..8191
    t_[idx] = W[(size_t)(pr * 64 + (idx >> 7)) * 128 + (idx & 127)];
  }
  __syncthreads();
  const int l = t & 63, ot = t >> 6;
  const int kh = l >> 5, o = ot * 32 + (l & 31);
  u8 buf[32];
#pragma unroll
  for (int b = 0; b < 32; ++b)
    buf[b] = f2e4m3(64.f * t_[(kh * 32 + b) * 128 + o]);
  u8* d = wfr + (size_t)pr * 8192 + ot * 2048 + l * 32;
  *(uint4*)d = *(uint4*)buf;
  *(uint4*)(d + 16) = *(uint4*)(buf + 16);
}

// ---------- init: out = bias ----------
__global__ __launch_bounds__(256)
void init_out(const float* __restrict__ bias, float* __restrict__ out) {
  const int i4 = blockIdx.x * 256 + threadIdx.x;
  float4 b = ((const float4*)bias)[i4 & 31];
  ((float4*)out)[i4] = b;
}

// ---------- main: 512 blocks(256thr) = 128 row-tiles(128r) x 4 quarters ----------
// Chunk-paired: GEMM1 = 8 MX/chunk; GEMM2 = 4 MX/pair (P in fp8, W fp8 x64 + HW scale 2^-6).
// cs 4-ring (pair dbuf); W via L2->regs; ONE barrier + stale vmcnt(0) per pair.
__global__ __launch_bounds__(256, 2)
void rbf_main(const u8* __restrict__ xfs, const u8* __restrict__ cfr,
              const u8* __restrict__ wfr, const float* __restrict__ csq_g,
              const float* __restrict__ xsq_g, float* __restrict__ out)
{
  __shared__ __align__(16) u8 cs[4][16384];   // center chunk 4-ring, 64 KB
  __shared__ __align__(16) float csq_l[1024];
  __shared__ __align__(16) float xsq_l[128];

  const int tid = threadIdx.x;
  const int lane = tid & 63;
  const int wv = tid >> 6;                 // wave 0..3 -> rows wv*32..+32
  const int l31 = lane & 31;
  const int h = lane >> 5;
  const int bid = blockIdx.x;
  const int chq = bid & 3;
  const size_t r0 = (size_t)(bid >> 2) * 128;

#define S_CS(cc) do { \
    const u8* sG_ = cfr + ((size_t)(chq * 32 + (cc)) << 14) + tid * 16; \
    u8* sL_ = &cs[(cc) & 3][0] + tid * 16; \
    GLOAD_LDS(sG_,         sL_); \
    GLOAD_LDS(sG_ + 4096,  sL_ + 4096); \
    GLOAD_LDS(sG_ + 8192,  sL_ + 8192); \
    GLOAD_LDS(sG_ + 12288, sL_ + 12288); \
  } while (0)

  // prologue staging: chunks 0,1 -> slots 0,1
  if (tid < 32) GLOAD_LDS(xsq_g + r0 + tid * 4, xsq_l + tid * 4);
  GLOAD_LDS(csq_g + chq * 1024 + tid * 4, csq_l + tid * 4);
  S_CS(0);
  S_CS(1);

  // x fragments: 8 x 32B (K=64 each)
  i32x8 xf8[8];
  {
    const u8* xb = xfs + ((size_t)((bid >> 2) * 4 + wv)) * 16384 + lane * 32;
#pragma unroll
    for (int P = 0; P < 8; ++P) {
      union { l64x2 q[2]; i32x8 v; } t;
      t.q[0] = *(const l64x2*)(xb + P * 2048);
      t.q[1] = *(const l64x2*)(xb + P * 2048 + 16);
      xf8[P] = t.v;
    }
  }

  asm volatile("s_waitcnt vmcnt(0)" ::: "memory");
  __builtin_amdgcn_s_barrier();
  __builtin_amdgcn_sched_barrier(0);

  const float xn = NB2 * xsq_l[wv * 32 + l31];

  const int swz = (lane >> 2) & 1;
  const int alo = lane * 32 + swz * 16;
  const int ahi = lane * 32 + (swz ^ 1) * 16;

  const f32x16 z16 = {0,0,0,0,0,0,0,0,0,0,0,0,0,0,0,0};
  f32x16 oa0 = z16, oa1 = z16, oa2 = z16, oa3 = z16;

// GEMM1 (swapped, MX) on chunk CC in ring slot SLOT, then exp+fp8-pack into O0..O3
#define G1EXP(CC, SLOT, O0, O1, O2, O3) do { \
    const u8* csb = &cs[SLOT][0]; \
    f32x16 s0 = z16, s1 = z16; \
    _Pragma("unroll") \
    for (int P = 0; P < 8; ++P) { \
      union { l64x2 q[2]; i32x8 v; } A; \
      A.q[0] = *(const l64x2*)(csb + P * 2048 + alo); \
      A.q[1] = *(const l64x2*)(csb + P * 2048 + ahi); \
      __builtin_amdgcn_s_setprio(1); \
      if (P & 1) s1 = MFS(A.v, xf8[P], s1); \
      else       s0 = MFS(A.v, xf8[P], s0); \
      __builtin_amdgcn_s_setprio(0); \
    } \
    f32x4 cq0 = *(const f32x4*)(csq_l + (CC) * 32 + 0  + 4 * h); \
    f32x4 cq1 = *(const f32x4*)(csq_l + (CC) * 32 + 8  + 4 * h); \
    f32x4 cq2 = *(const f32x4*)(csq_l + (CC) * 32 + 16 + 4 * h); \
    f32x4 cq3 = *(const f32x4*)(csq_l + (CC) * 32 + 24 + 4 * h); \
    float e[16]; \
    _Pragma("unroll") \
    for (int r = 0; r < 16; ++r) { \
      const float cq = (r < 4 ? cq0[r] : r < 8 ? cq1[r-4] : r < 12 ? cq2[r-8] : cq3[r-12]); \
      e[r] = __builtin_amdgcn_exp2f(fmaf(s0[r] + s1[r], P2C, fmaf(cq, NB2, xn))); \
    } \
    O0 = pk4(e[0],  e[1],  e[2],  e[3]); \
    O1 = pk4(e[4],  e[5],  e[6],  e[7]); \
    O2 = pk4(e[8],  e[9],  e[10], e[11]); \
    O3 = pk4(e[12], e[13], e[14], e[15]); \
  } while (0)

#pragma unroll 1
  for (int t = 0; t < 16; ++t) {
    // ---- W pair t -> regs (coalesced, L2-hot; consumed ~4000cy later) ----
    const u8* wgb = wfr + ((size_t)(chq * 16 + t) << 13) + lane * 32;
    union { l64x2 q[2]; i32x8 v; } w0, w1, w2, w3;
    w0.q[0] = *(const l64x2*)(wgb);        w0.q[1] = *(const l64x2*)(wgb + 16);
    w1.q[0] = *(const l64x2*)(wgb + 2048); w1.q[1] = *(const l64x2*)(wgb + 2064);
    w2.q[0] = *(const l64x2*)(wgb + 4096); w2.q[1] = *(const l64x2*)(wgb + 4112);
    w3.q[0] = *(const l64x2*)(wgb + 6144); w3.q[1] = *(const l64x2*)(wgb + 6160);
    __builtin_amdgcn_sched_barrier(0);
    // ---- stage next pair into the free ring slots ----
    if (t < 15) { S_CS(2 * t + 2); S_CS(2 * t + 3); }
    __builtin_amdgcn_sched_barrier(0);

    unsigned D0, D1, D2, D3, E0, E1, E2, E3;
    G1EXP(2 * t,     (2 * t) & 3,     D0, D1, D2, D3);
    G1EXP(2 * t + 1, (2 * t + 1) & 3, E0, E1, E2, E3);

    // assemble pair A-operand: A[2i]=D_i, A[2i+1]=E_i after half-exchange
    pswap(D0, E0); pswap(D1, E1); pswap(D2, E2); pswap(D3, E3);
    union { unsigned u[8]; i32x8 v; } PA;
    PA.u[0] = D0; PA.u[1] = E0; PA.u[2] = D1; PA.u[3] = E1;
    PA.u[4] = D2; PA.u[5] = E2; PA.u[6] = D3; PA.u[7] = E3;

    // ---- GEMM2: 4 MX insts, K=64 (the pair), W scale 2^-6 ----
    __builtin_amdgcn_s_setprio(1);
    oa0 = MFS2(PA.v, w0.v, oa0);
    oa1 = MFS2(PA.v, w1.v, oa1);
    oa2 = MFS2(PA.v, w2.v, oa2);
    oa3 = MFS2(PA.v, w3.v, oa3);
    __builtin_amdgcn_s_setprio(0);

    // ring-slot reuse guard; staged DMAs are ~whole-iter old -> no stall
    asm volatile("s_waitcnt vmcnt(0)" ::: "memory");
    __builtin_amdgcn_s_barrier();
    __builtin_amdgcn_sched_barrier(0);
  }

  // epilogue: out += partial; D rows m=(r&3)+8*(r>>2)+4h, cols o=ot*32+l31
#pragma unroll
  for (int r = 0; r < 16; ++r) {
    const int m = wv * 32 + (r & 3) + 8 * (r >> 2) + 4 * h;
    float* op = &out[(r0 + m) * 128 + l31];
    atomicAdd(op,      oa0[r]);
    atomicAdd(op + 32, oa1[r]);
    atomicAdd(op + 64, oa2[r]);
    atomicAdd(op + 96, oa3[r]);
  }
#undef S_CS
#undef G1EXP
}

extern "C" void kernel_launch(void* const* d_in, const int* in_sizes, int n_in,
                              void* d_out, int out_size, void* d_ws, size_t ws_size,
                              hipStream_t stream) {
  (void)in_sizes; (void)n_in; (void)out_size; (void)ws_size;
  const float* x   = (const float*)d_in[0];
  const float* cen = (const float*)d_in[1];
  const float* W   = (const float*)d_in[2];
  const float* b   = (const float*)d_in[3];
  u8* xfs = (u8*)d_ws;                          // 8 MB (x K=64 frag-stream)
  u8* cfr = xfs + (size_t)16384 * 512;          // 2 MB (center K=64 frag-stream)
  u8* wfr = cfr + (size_t)4096 * 512;           // 512 KB (W fp8 x64 pair-stream)
  float* csq = (float*)(wfr + (size_t)64 * 8192);  // 16 KB
  float* xsq = csq + 4096;                      // 64 KB
  prep_x8<<<2048, 512, 0, stream>>>(x, xfs, xsq);
  prep_cen<<<1024, 256, 0, stream>>>(cen, cfr, csq);
  prep_w<<<64, 256, 0, stream>>>(W, wfr);
  init_out<<<2048, 256, 0, stream>>>(b, (float*)d_out);
  rbf_main<<<512, 256, 0, stream>>>(xfs, cfr, wfr, csq, xsq, (float*)d_out);
}